// Round 6
// baseline (69.298 us; speedup 1.0000x reference)
//
#include <hip/hip_runtime.h>

// popcount of ballot bits strictly below this lane (wave64)
__device__ __forceinline__ int lanes_below(unsigned long long m) {
    return __builtin_amdgcn_mbcnt_hi((unsigned)(m >> 32),
           __builtin_amdgcn_mbcnt_lo((unsigned)m, 0u));
}

// Masked MSE with ragged alignment — one 512-thread block per row.
// 1) load mask+pred (4 independent vector loads)
// 2) rank via ballot+mbcnt (pure VALU), wave totals exchanged once via LDS
// 3) scatter masked pred into comp[rank] in LDS (fire-and-forget ds_write)
// 4) barrier; thread t reads comp[8t..8t+8) (ds_read_b128 x2) and
//    target[8t..8t+8) (coalesced float4 x2, only threads with 8t < total)
// -> no scattered global gather at all; target read exactly once, linearly.
// 5) block reduce; one float atomicAdd per block (no second kernel).
__global__ __launch_bounds__(512, 8) void masked_mse_rows(
    const float* __restrict__ pred,
    const float* __restrict__ target,
    const int*   __restrict__ mask,
    float*       __restrict__ out,
    int S)
{
    const int tid  = threadIdx.x;
    const int lane = tid & 63;
    const int wid  = tid >> 6;          // 0..7
    const int row  = blockIdx.x;

    const float4* __restrict__ p4 = reinterpret_cast<const float4*>(pred + (size_t)row * S);
    const int4*   __restrict__ m4 = reinterpret_cast<const int4*>(mask + (size_t)row * S);
    const float*  __restrict__ trow = target + (size_t)row * S;

    __shared__ __align__(16) float comp[4096];
    __shared__ int   tsum[16];
    __shared__ float facc[8];

    // all four big loads independent, issued together
    const int4   ma = m4[tid];
    const int4   mb = m4[tid + 512];
    const float4 pa = p4[tid];
    const float4 pb = p4[tid + 512];

    const int c0 = (ma.x != 0), c1 = (ma.y != 0), c2 = (ma.z != 0), c3 = (ma.w != 0);
    const int c4 = (mb.x != 0), c5 = (mb.y != 0), c6 = (mb.z != 0), c7 = (mb.w != 0);

    const unsigned long long a0 = __ballot(c0);
    const unsigned long long a1 = __ballot(c1);
    const unsigned long long a2 = __ballot(c2);
    const unsigned long long a3 = __ballot(c3);
    const unsigned long long b0 = __ballot(c4);
    const unsigned long long b1 = __ballot(c5);
    const unsigned long long b2 = __ballot(c6);
    const unsigned long long b3 = __ballot(c7);

    const int pref_a = lanes_below(a0) + lanes_below(a1) + lanes_below(a2) + lanes_below(a3);
    const int pref_b = lanes_below(b0) + lanes_below(b1) + lanes_below(b2) + lanes_below(b3);
    const int tot_a  = __popcll(a0) + __popcll(a1) + __popcll(a2) + __popcll(a3);
    const int tot_b  = __popcll(b0) + __popcll(b1) + __popcll(b2) + __popcll(b3);

    if (lane == 0) { tsum[wid] = tot_a; tsum[8 + wid] = tot_b; }
    __syncthreads();

    int base_a = 0, pre_b = 0, sumA = 0, total = 0;
    #pragma unroll
    for (int w = 0; w < 8; ++w) {
        const int va = tsum[w], vb = tsum[8 + w];
        base_a += (w < wid) ? va : 0;
        pre_b  += (w < wid) ? vb : 0;
        sumA   += va;
        total  += va + vb;
    }
    const int base_b = sumA + pre_b;

    // scatter masked pred into comp[rank] (independent stores, no wait chain)
    {
        int r = base_a + pref_a;
        if (c0) { comp[r] = pa.x; ++r; }
        if (c1) { comp[r] = pa.y; ++r; }
        if (c2) { comp[r] = pa.z; ++r; }
        if (c3) { comp[r] = pa.w; }
    }
    {
        int r = base_b + pref_b;
        if (c4) { comp[r] = pb.x; ++r; }
        if (c5) { comp[r] = pb.y; ++r; }
        if (c6) { comp[r] = pb.z; ++r; }
        if (c7) { comp[r] = pb.w; }
    }
    __syncthreads();

    float acc = 0.0f;
    const int k = total - 8 * tid;      // #valid among this thread's 8 slots
    if (k > 0) {                        // wave-uniform except one boundary wave
        const float4* c4p = reinterpret_cast<const float4*>(comp);
        const float4* t4p = reinterpret_cast<const float4*>(trow);
        const float4 cv0 = c4p[2 * tid];
        const float4 cv1 = c4p[2 * tid + 1];
        const float4 tv0 = t4p[2 * tid];      // coalesced, exactly-once
        const float4 tv1 = t4p[2 * tid + 1];
        float d;
        d = cv0.x - tv0.x; acc += (0 < k) ? d * d : 0.0f;
        d = cv0.y - tv0.y; acc += (1 < k) ? d * d : 0.0f;
        d = cv0.z - tv0.z; acc += (2 < k) ? d * d : 0.0f;
        d = cv0.w - tv0.w; acc += (3 < k) ? d * d : 0.0f;
        d = cv1.x - tv1.x; acc += (4 < k) ? d * d : 0.0f;
        d = cv1.y - tv1.y; acc += (5 < k) ? d * d : 0.0f;
        d = cv1.z - tv1.z; acc += (6 < k) ? d * d : 0.0f;
        d = cv1.w - tv1.w; acc += (7 < k) ? d * d : 0.0f;
    }

    // wave reduce, then cross-wave via LDS, one atomic per block
    #pragma unroll
    for (int off = 32; off > 0; off >>= 1) acc += __shfl_down(acc, off, 64);
    if (lane == 0) facc[wid] = acc;
    __syncthreads();
    if (tid == 0) {
        float s = 0.0f;
        #pragma unroll
        for (int w = 0; w < 8; ++w) s += facc[w];
        atomicAdd(out, s);
    }
}

extern "C" void kernel_launch(void* const* d_in, const int* in_sizes, int n_in,
                              void* d_out, int out_size, void* d_ws, size_t ws_size,
                              hipStream_t stream) {
    const float* pred   = (const float*)d_in[0];
    const float* target = (const float*)d_in[1];
    const int*   mask   = (const int*)d_in[2];
    float* out = (float*)d_out;

    const int S = 4096;
    const int B = in_sizes[0] / S;

    hipMemsetAsync(out, 0, sizeof(float) * out_size, stream);
    masked_mse_rows<<<B, 512, 0, stream>>>(pred, target, mask, out, S);
}

// Round 7
// 31.316 us; speedup vs baseline: 2.2129x; 2.2129x over previous
//
#include <hip/hip_runtime.h>

// popcount of ballot bits strictly below this lane (wave64)
__device__ __forceinline__ int lanes_below(unsigned long long m) {
    return __builtin_amdgcn_mbcnt_hi((unsigned)(m >> 32),
           __builtin_amdgcn_mbcnt_lo((unsigned)m, 0u));
}

// Masked MSE with ragged alignment — one 512-thread block per row.
// 1) load mask+pred (4 independent vector loads)
// 2) rank via ballot+mbcnt (pure VALU), wave totals exchanged once via LDS
// 3) scatter masked pred into comp[rank] in LDS (fire-and-forget ds_write)
// 4) barrier; thread t reads comp[8t..8t+8) (ds_read_b128 x2) and
//    target[8t..8t+8) (coalesced float4 x2, only threads with 8t < total)
// 5) block reduce -> row_sums[row]; separate tiny kernel does the final sum
//    (NO single-address atomics: 4096 contended fadds cost ~+40us in R6).
__global__ __launch_bounds__(512, 8) void masked_mse_rows(
    const float* __restrict__ pred,
    const float* __restrict__ target,
    const int*   __restrict__ mask,
    float*       __restrict__ row_sums,
    int S)
{
    const int tid  = threadIdx.x;
    const int lane = tid & 63;
    const int wid  = tid >> 6;          // 0..7
    const int row  = blockIdx.x;

    const float4* __restrict__ p4 = reinterpret_cast<const float4*>(pred + (size_t)row * S);
    const int4*   __restrict__ m4 = reinterpret_cast<const int4*>(mask + (size_t)row * S);
    const float*  __restrict__ trow = target + (size_t)row * S;

    __shared__ __align__(16) float comp[4096];
    __shared__ int   tsum[16];
    __shared__ float facc[8];

    // all four big loads independent, issued together
    const int4   ma = m4[tid];
    const int4   mb = m4[tid + 512];
    const float4 pa = p4[tid];
    const float4 pb = p4[tid + 512];

    const int c0 = (ma.x != 0), c1 = (ma.y != 0), c2 = (ma.z != 0), c3 = (ma.w != 0);
    const int c4 = (mb.x != 0), c5 = (mb.y != 0), c6 = (mb.z != 0), c7 = (mb.w != 0);

    const unsigned long long a0 = __ballot(c0);
    const unsigned long long a1 = __ballot(c1);
    const unsigned long long a2 = __ballot(c2);
    const unsigned long long a3 = __ballot(c3);
    const unsigned long long b0 = __ballot(c4);
    const unsigned long long b1 = __ballot(c5);
    const unsigned long long b2 = __ballot(c6);
    const unsigned long long b3 = __ballot(c7);

    const int pref_a = lanes_below(a0) + lanes_below(a1) + lanes_below(a2) + lanes_below(a3);
    const int pref_b = lanes_below(b0) + lanes_below(b1) + lanes_below(b2) + lanes_below(b3);
    const int tot_a  = __popcll(a0) + __popcll(a1) + __popcll(a2) + __popcll(a3);
    const int tot_b  = __popcll(b0) + __popcll(b1) + __popcll(b2) + __popcll(b3);

    if (lane == 0) { tsum[wid] = tot_a; tsum[8 + wid] = tot_b; }
    __syncthreads();

    int base_a = 0, pre_b = 0, sumA = 0, total = 0;
    #pragma unroll
    for (int w = 0; w < 8; ++w) {
        const int va = tsum[w], vb = tsum[8 + w];
        base_a += (w < wid) ? va : 0;
        pre_b  += (w < wid) ? vb : 0;
        sumA   += va;
        total  += va + vb;
    }
    const int base_b = sumA + pre_b;

    // scatter masked pred into comp[rank] (independent stores, no wait chain)
    {
        int r = base_a + pref_a;
        if (c0) { comp[r] = pa.x; ++r; }
        if (c1) { comp[r] = pa.y; ++r; }
        if (c2) { comp[r] = pa.z; ++r; }
        if (c3) { comp[r] = pa.w; }
    }
    {
        int r = base_b + pref_b;
        if (c4) { comp[r] = pb.x; ++r; }
        if (c5) { comp[r] = pb.y; ++r; }
        if (c6) { comp[r] = pb.z; ++r; }
        if (c7) { comp[r] = pb.w; }
    }
    __syncthreads();

    float acc = 0.0f;
    const int k = total - 8 * tid;      // #valid among this thread's 8 slots
    if (k > 0) {                        // wave-uniform except one boundary wave
        const float4* c4p = reinterpret_cast<const float4*>(comp);
        const float4* t4p = reinterpret_cast<const float4*>(trow);
        const float4 cv0 = c4p[2 * tid];
        const float4 cv1 = c4p[2 * tid + 1];
        const float4 tv0 = t4p[2 * tid];      // coalesced, exactly-once
        const float4 tv1 = t4p[2 * tid + 1];
        float d;
        d = cv0.x - tv0.x; acc += (0 < k) ? d * d : 0.0f;
        d = cv0.y - tv0.y; acc += (1 < k) ? d * d : 0.0f;
        d = cv0.z - tv0.z; acc += (2 < k) ? d * d : 0.0f;
        d = cv0.w - tv0.w; acc += (3 < k) ? d * d : 0.0f;
        d = cv1.x - tv1.x; acc += (4 < k) ? d * d : 0.0f;
        d = cv1.y - tv1.y; acc += (5 < k) ? d * d : 0.0f;
        d = cv1.z - tv1.z; acc += (6 < k) ? d * d : 0.0f;
        d = cv1.w - tv1.w; acc += (7 < k) ? d * d : 0.0f;
    }

    // wave reduce, then cross-wave via LDS; lane 0 of block writes row partial
    #pragma unroll
    for (int off = 32; off > 0; off >>= 1) acc += __shfl_down(acc, off, 64);
    if (lane == 0) facc[wid] = acc;
    __syncthreads();
    if (tid == 0) {
        float s = 0.0f;
        #pragma unroll
        for (int w = 0; w < 8; ++w) s += facc[w];
        row_sums[row] = s;
    }
}

// Deterministic final reduce of B row partials into d_out[0].
__global__ __launch_bounds__(1024) void reduce_rows(
    const float* __restrict__ row_sums, float* __restrict__ out, int n)
{
    const int tid = threadIdx.x;
    float acc = 0.0f;
    const int n4 = n >> 2;
    const float4* rs4 = reinterpret_cast<const float4*>(row_sums);
    for (int i = tid; i < n4; i += 1024) {
        float4 v = rs4[i];
        acc += (v.x + v.y) + (v.z + v.w);
    }
    for (int i = (n4 << 2) + tid; i < n; i += 1024) acc += row_sums[i];

    #pragma unroll
    for (int off = 32; off > 0; off >>= 1) acc += __shfl_down(acc, off, 64);
    __shared__ float facc[16];
    if ((tid & 63) == 0) facc[tid >> 6] = acc;
    __syncthreads();
    if (tid == 0) {
        float s = 0.0f;
        #pragma unroll
        for (int w = 0; w < 16; ++w) s += facc[w];
        out[0] = s;
    }
}

extern "C" void kernel_launch(void* const* d_in, const int* in_sizes, int n_in,
                              void* d_out, int out_size, void* d_ws, size_t ws_size,
                              hipStream_t stream) {
    const float* pred   = (const float*)d_in[0];
    const float* target = (const float*)d_in[1];
    const int*   mask   = (const int*)d_in[2];
    float* out = (float*)d_out;
    float* row_sums = (float*)d_ws;

    const int S = 4096;
    const int B = in_sizes[0] / S;

    masked_mse_rows<<<B, 512, 0, stream>>>(pred, target, mask, row_sums, S);
    reduce_rows<<<1, 1024, 0, stream>>>(row_sums, out, B);
}